// Round 4
// baseline (104.552 us; speedup 1.0000x reference)
//
#include <hip/hip_runtime.h>
#include <float.h>
#include <math.h>

#define Ln 2048
#define Bn 64
#define Cn 512
#define Qn 512
#define Vn 512
#define NO 1536   // C*KW

// workspace layout (in floats)
#define OFF_KERN 0                               // kern[3][B][C] = 98304
#define OFF_ABT  98304                           // aBT[b][t]     = 131072
#define OFF_GP   (98304 + 131072)                // gpart[4][B][NO] = 393216

typedef float f4 __attribute__((ext_vector_type(4)));
typedef float f2 __attribute__((ext_vector_type(2)));

__device__ __forceinline__ float dot8(f4 a0, f4 a1, f4 b0, f4 b1) {
    f4 p = a0 * b0;
    p += a1 * b1;
    return (p.x + p.y) + (p.z + p.w);
}

// ---------------- K1: gpart[ks][b][o] = sum_{k in split} q[b,k] W[o,k]
__global__ __launch_bounds__(256) void k1_gemm(const float* __restrict__ q,
                                               const float* __restrict__ W,
                                               float* __restrict__ gpart) {
    __shared__ __align__(16) float qs[64][68];
    __shared__ __align__(16) float wsm[64][68];
    const int o0 = blockIdx.x * 64;
    const int k0 = blockIdx.y * 128;
    const int tid = threadIdx.x;
    const int ty = tid >> 4, tx = tid & 15;

    f4 accv[4][4];
#pragma unroll
    for (int i = 0; i < 4; ++i)
#pragma unroll
        for (int j = 0; j < 4; ++j) accv[i][j] = (f4)0.f;

    for (int kc = 0; kc < 128; kc += 64) {
#pragma unroll
        for (int r = 0; r < 4; ++r) {
            int idx = tid + r * 256;
            int row = idx >> 4;
            int c4 = (idx & 15) << 2;
            float4 vq = *(const float4*)&q[row * Qn + k0 + kc + c4];
            qs[row][c4 + 0] = vq.x; qs[row][c4 + 1] = vq.y;
            qs[row][c4 + 2] = vq.z; qs[row][c4 + 3] = vq.w;
            float4 vw = *(const float4*)&W[(o0 + row) * Qn + k0 + kc + c4];
            wsm[row][c4 + 0] = vw.x; wsm[row][c4 + 1] = vw.y;
            wsm[row][c4 + 2] = vw.z; wsm[row][c4 + 3] = vw.w;
        }
        __syncthreads();
#pragma unroll
        for (int kk4 = 0; kk4 < 16; ++kk4) {
            f4 qf[4], wf[4];
#pragma unroll
            for (int i = 0; i < 4; ++i) qf[i] = *(const f4*)&qs[ty * 4 + i][kk4 * 4];
#pragma unroll
            for (int j = 0; j < 4; ++j) wf[j] = *(const f4*)&wsm[tx * 4 + j][kk4 * 4];
#pragma unroll
            for (int i = 0; i < 4; ++i)
#pragma unroll
                for (int j = 0; j < 4; ++j) accv[i][j] += qf[i] * wf[j];
        }
        __syncthreads();
    }
#pragma unroll
    for (int i = 0; i < 4; ++i) {
        float4 w4;
        f4 p;
        p = accv[i][0]; w4.x = (p.x + p.y) + (p.z + p.w);
        p = accv[i][1]; w4.y = (p.x + p.y) + (p.z + p.w);
        p = accv[i][2]; w4.z = (p.x + p.y) + (p.z + p.w);
        p = accv[i][3]; w4.w = (p.x + p.y) + (p.z + p.w);
        *(float4*)&gpart[(blockIdx.y * 64 + ty * 4 + i) * NO + o0 + tx * 4] = w4;
    }
}

// ---------------- K1b: reduce k-splits + bias, transpose to kern[w][b][c]
__global__ __launch_bounds__(256) void k1b_reduce(const float* __restrict__ gpart,
                                                  const float* __restrict__ bias,
                                                  float* __restrict__ kern) {
    int idx = blockIdx.x * 256 + threadIdx.x;
    if (idx >= 3 * Bn * Cn) return;
    int w = idx / (Bn * Cn);
    int rem = idx - w * (Bn * Cn);
    int b = rem >> 9;
    int c = rem & 511;
    int o = c * 3 + w;
    float s = bias[o];
#pragma unroll
    for (int ks = 0; ks < 4; ++ks) s += gpart[(ks * Bn + b) * NO + o];
    kern[idx] = s;
}

// ---------------- K2: fused 3-tap conv-dot, sliding window. wave = (b, 32 t's)
__global__ __launch_bounds__(256) void k2_dots(const float* __restrict__ kin,
                                               const float* __restrict__ kern,
                                               float* __restrict__ aBT) {
    const int wid = (blockIdx.x << 2) + (threadIdx.x >> 6);
    const int lane = threadIdx.x & 63;
    const int b = wid & 63;
    const int t0 = (wid >> 6) << 5;   // 32 t per wave

    f4 kwA[3], kwB[3];
#pragma unroll
    for (int w = 0; w < 3; ++w) {
        const f4* p = (const f4*)(kern + (w * Bn + b) * Cn);
        kwA[w] = p[lane];
        kwB[w] = p[64 + lane];
    }

    float al[32];
#pragma unroll
    for (int j = 0; j < 32; ++j) al[j] = 0.f;

    if (t0 > 0) {
        const f4* kr = (const f4*)(kin + ((size_t)(t0 - 1) * Bn + b) * Cn);
        f4 a = __builtin_nontemporal_load(kr + lane);
        f4 c = __builtin_nontemporal_load(kr + 64 + lane);
        al[0] += dot8(a, c, kwA[0], kwB[0]);
    }
#pragma unroll
    for (int j = 0; j < 32; ++j) {
        const int t = t0 + j;
        const f4* kr = (const f4*)(kin + ((size_t)t * Bn + b) * Cn);
        f4 a = __builtin_nontemporal_load(kr + lane);
        f4 c = __builtin_nontemporal_load(kr + 64 + lane);
        if (j + 1 < 32) al[j + 1] += dot8(a, c, kwA[0], kwB[0]);
        al[j] += dot8(a, c, kwA[1], kwB[1]);
        if (j >= 1) al[j - 1] += dot8(a, c, kwA[2], kwB[2]);
    }
    if (t0 + 32 < Ln) {
        const f4* kr = (const f4*)(kin + ((size_t)(t0 + 32) * Bn + b) * Cn);
        f4 a = __builtin_nontemporal_load(kr + lane);
        f4 c = __builtin_nontemporal_load(kr + 64 + lane);
        al[31] += dot8(a, c, kwA[2], kwB[2]);
    }

#pragma unroll
    for (int j = 0; j < 32; ++j) {
        float s = al[j];
#pragma unroll
        for (int off = 32; off; off >>= 1) s += __shfl_xor(s, off);
        al[j] = s;
    }
    if (lane == 0) {
        float* dst = aBT + b * Ln + t0;
#pragma unroll
        for (int j = 0; j < 8; ++j) {
            f4 o;
            o.x = al[4 * j]; o.y = al[4 * j + 1]; o.z = al[4 * j + 2]; o.w = al[4 * j + 3];
            *(f4*)&dst[4 * j] = o;
        }
    }
}

// ---------------- KC: per-b stats + emit + sparse PV -> attend. one block per b.
__global__ __launch_bounds__(256) void kC(const float* __restrict__ aBT,
                                          const int* __restrict__ kmask,
                                          const float* __restrict__ v,
                                          float* __restrict__ out_a,
                                          float* __restrict__ out_e,
                                          float* __restrict__ out_att) {
    const int b = blockIdx.x;
    const int tid = threadIdx.x;
    __shared__ float es[2048];
    __shared__ int lst[2048];
    __shared__ unsigned long long bm[32];
    __shared__ float red[4];
    __shared__ int cnt;

    float av[8];
    int m[8];
    float lmax = -FLT_MAX;
#pragma unroll
    for (int i = 0; i < 8; ++i) {
        int t = i * 256 + tid;
        av[i] = aBT[b * Ln + t];
        m[i] = kmask[t * Bn + b];
        if (m[i]) lmax = fmaxf(lmax, av[i]);
    }
#pragma unroll
    for (int off = 32; off; off >>= 1) lmax = fmaxf(lmax, __shfl_xor(lmax, off));
    if ((tid & 63) == 0) red[tid >> 6] = lmax;
    __syncthreads();
    const float mx = fmaxf(fmaxf(red[0], red[1]), fmaxf(red[2], red[3]));
    __syncthreads();

    float ev[8];
    float lsum = 0.f;
#pragma unroll
    for (int i = 0; i < 8; ++i) {
        ev[i] = m[i] ? __expf(av[i] - mx) : 0.f;
        lsum += ev[i];
    }
#pragma unroll
    for (int off = 32; off; off >>= 1) lsum += __shfl_xor(lsum, off);
    if ((tid & 63) == 0) red[tid >> 6] = lsum;
    __syncthreads();
    const float inv = 1.f / (red[0] + red[1] + red[2] + red[3]);

#pragma unroll
    for (int i = 0; i < 8; ++i) {
        const int t = i * 256 + tid;
        const float e = ev[i] * inv;
        es[t] = e;
        out_a[t * Bn + b] = av[i];
        out_e[t * Bn + b] = e;
        unsigned long long bal = __ballot(e != 0.f);
        if ((tid & 63) == 0) bm[i * 4 + (tid >> 6)] = bal;
    }
    __syncthreads();

    if (tid == 0) {
        int c = 0;
        for (int w2 = 0; w2 < 32; ++w2) {
            unsigned long long mm = bm[w2];
            while (mm) {
                int bit = __ffsll(mm) - 1;
                mm &= mm - 1;
                lst[c++] = w2 * 64 + bit;
            }
        }
        cnt = c;
    }
    __syncthreads();
    const int n = cnt;

    f2 a0, a1, a2, a3;
    a0 = (f2)0.f; a1 = (f2)0.f; a2 = (f2)0.f; a3 = (f2)0.f;
    int i = 0;
    for (; i + 4 <= n; i += 4) {
        const int t0 = lst[i], t1 = lst[i + 1], t2 = lst[i + 2], t3 = lst[i + 3];
        const float e0 = es[t0], e1 = es[t1], e2 = es[t2], e3 = es[t3];
        const f2 v0 = ((const f2*)(v + ((size_t)t0 * Bn + b) * Vn))[tid];
        const f2 v1 = ((const f2*)(v + ((size_t)t1 * Bn + b) * Vn))[tid];
        const f2 v2 = ((const f2*)(v + ((size_t)t2 * Bn + b) * Vn))[tid];
        const f2 v3 = ((const f2*)(v + ((size_t)t3 * Bn + b) * Vn))[tid];
        a0 += e0 * v0;
        a1 += e1 * v1;
        a2 += e2 * v2;
        a3 += e3 * v3;
    }
    for (; i < n; ++i) {
        const int t0 = lst[i];
        const float e0 = es[t0];
        const f2 v0 = ((const f2*)(v + ((size_t)t0 * Bn + b) * Vn))[tid];
        a0 += e0 * v0;
    }
    f2 s = (a0 + a1) + (a2 + a3);
    *(f2*)&out_att[b * Vn + tid * 2] = s;
}

extern "C" void kernel_launch(void* const* d_in, const int* in_sizes, int n_in,
                              void* d_out, int out_size, void* d_ws, size_t ws_size,
                              hipStream_t stream) {
    const float* q = (const float*)d_in[0];
    const float* k = (const float*)d_in[1];
    const float* v = (const float*)d_in[2];
    const int* kmask = (const int*)d_in[3];
    const float* W = (const float*)d_in[4];
    const float* bias = (const float*)d_in[5];

    float* out = (float*)d_out;
    float* out_a = out;                      // [L, B]
    float* out_e = out + Ln * Bn;            // [L, B]
    float* out_att = out + 2 * Ln * Bn;      // [B, V]

    float* ws = (float*)d_ws;
    float* kern = ws + OFF_KERN;
    float* aBT = ws + OFF_ABT;
    float* gpart = ws + OFF_GP;

    k1_gemm<<<dim3(24, 4), 256, 0, stream>>>(q, W, gpart);
    k1b_reduce<<<(3 * Bn * Cn + 255) / 256, 256, 0, stream>>>(gpart, bias, kern);
    k2_dots<<<1024, 256, 0, stream>>>(k, kern, aBT);
    kC<<<Bn, 256, 0, stream>>>(aBT, kmask, v, out_a, out_e, out_att);
}

// Round 5
// 96.377 us; speedup vs baseline: 1.0848x; 1.0848x over previous
//
#include <hip/hip_runtime.h>
#include <float.h>
#include <math.h>

#define Ln 2048
#define Bn 64
#define Cn 512
#define Qn 512
#define Vn 512
#define NO 1536   // C*KW

#define DROW 2064   // padded dpl row: 8 front pad + 2048 + 8 tail pad
#define DPAD 8

// workspace layout (in floats)
#define OFF_KERN 0                                   // kern[3][B][C]   = 98304
#define OFF_DPL  98304                               // dplP[3][B][DROW]= 396288
#define OFF_ET   (98304 + 396288)                    // eT[b][t]        = 131072
#define OFF_STAT (98304 + 396288 + 131072)           // stats[B][2]     = 128
#define OFF_SCR  (98304 + 396288 + 131072 + 128)     // gpart(393216) / vpart(262144)

typedef float f4 __attribute__((ext_vector_type(4)));
typedef float f2 __attribute__((ext_vector_type(2)));

// ---------------- K1: gpart[ks][b][o] = sum_{k in split} q[b,k] W[o,k]
__global__ __launch_bounds__(256) void k1_gemm(const float* __restrict__ q,
                                               const float* __restrict__ W,
                                               float* __restrict__ gpart) {
    __shared__ __align__(16) float qs[64][68];
    __shared__ __align__(16) float wsm[64][68];
    const int o0 = blockIdx.x * 64;
    const int k0 = blockIdx.y * 128;
    const int tid = threadIdx.x;
    const int ty = tid >> 4, tx = tid & 15;

    f4 accv[4][4];
#pragma unroll
    for (int i = 0; i < 4; ++i)
#pragma unroll
        for (int j = 0; j < 4; ++j) accv[i][j] = (f4)0.f;

    for (int kc = 0; kc < 128; kc += 64) {
#pragma unroll
        for (int r = 0; r < 4; ++r) {
            int idx = tid + r * 256;
            int row = idx >> 4;
            int c4 = (idx & 15) << 2;
            float4 vq = *(const float4*)&q[row * Qn + k0 + kc + c4];
            qs[row][c4 + 0] = vq.x; qs[row][c4 + 1] = vq.y;
            qs[row][c4 + 2] = vq.z; qs[row][c4 + 3] = vq.w;
            float4 vw = *(const float4*)&W[(o0 + row) * Qn + k0 + kc + c4];
            wsm[row][c4 + 0] = vw.x; wsm[row][c4 + 1] = vw.y;
            wsm[row][c4 + 2] = vw.z; wsm[row][c4 + 3] = vw.w;
        }
        __syncthreads();
#pragma unroll
        for (int kk4 = 0; kk4 < 16; ++kk4) {
            f4 qf[4], wf[4];
#pragma unroll
            for (int i = 0; i < 4; ++i) qf[i] = *(const f4*)&qs[ty * 4 + i][kk4 * 4];
#pragma unroll
            for (int j = 0; j < 4; ++j) wf[j] = *(const f4*)&wsm[tx * 4 + j][kk4 * 4];
#pragma unroll
            for (int i = 0; i < 4; ++i)
#pragma unroll
                for (int j = 0; j < 4; ++j) accv[i][j] += qf[i] * wf[j];
        }
        __syncthreads();
    }
#pragma unroll
    for (int i = 0; i < 4; ++i) {
        float4 w4;
        f4 p;
        p = accv[i][0]; w4.x = (p.x + p.y) + (p.z + p.w);
        p = accv[i][1]; w4.y = (p.x + p.y) + (p.z + p.w);
        p = accv[i][2]; w4.z = (p.x + p.y) + (p.z + p.w);
        p = accv[i][3]; w4.w = (p.x + p.y) + (p.z + p.w);
        *(float4*)&gpart[(blockIdx.y * 64 + ty * 4 + i) * NO + o0 + tx * 4] = w4;
    }
}

// ---------------- K1b: reduce k-splits + bias, transpose to kern[w][b][c]
__global__ __launch_bounds__(256) void k1b_reduce(const float* __restrict__ gpart,
                                                  const float* __restrict__ bias,
                                                  float* __restrict__ kern) {
    int idx = blockIdx.x * 256 + threadIdx.x;
    if (idx >= 3 * Bn * Cn) return;
    int w = idx / (Bn * Cn);
    int rem = idx - w * (Bn * Cn);
    int b = rem >> 9;
    int c = rem & 511;
    int o = c * 3 + w;
    float s = bias[o];
#pragma unroll
    for (int ks = 0; ks < 4; ++ks) s += gpart[(ks * Bn + b) * NO + o];
    kern[idx] = s;
}

// ---------------- K2 (R2 variant): dplP[w][b][8+t] = k[t,b,:]·kern[w][b][:]; wave=(b, 8 t's)
__global__ __launch_bounds__(256) void k2_dots(const float* __restrict__ kin,
                                               const float* __restrict__ kern,
                                               float* __restrict__ dplP) {
    const int wid = (blockIdx.x << 2) + (threadIdx.x >> 6);
    const int lane = threadIdx.x & 63;
    const int b = wid & 63;
    const int t0 = (wid >> 6) << 3;

    f4 kwA[3], kwB[3];
#pragma unroll
    for (int w = 0; w < 3; ++w) {
        const f4* p = (const f4*)(kern + (w * Bn + b) * Cn);
        kwA[w] = p[lane];
        kwB[w] = p[64 + lane];
    }
#pragma unroll
    for (int ti = 0; ti < 8; ++ti) {
        const int t = t0 + ti;
        const f4* kr = (const f4*)(kin + ((size_t)t * Bn + b) * Cn);
        f4 a = __builtin_nontemporal_load(kr + lane);
        f4 c = __builtin_nontemporal_load(kr + 64 + lane);
        float acc0 = a.x * kwA[0].x + a.y * kwA[0].y + a.z * kwA[0].z + a.w * kwA[0].w
                   + c.x * kwB[0].x + c.y * kwB[0].y + c.z * kwB[0].z + c.w * kwB[0].w;
        float acc1 = a.x * kwA[1].x + a.y * kwA[1].y + a.z * kwA[1].z + a.w * kwA[1].w
                   + c.x * kwB[1].x + c.y * kwB[1].y + c.z * kwB[1].z + c.w * kwB[1].w;
        float acc2 = a.x * kwA[2].x + a.y * kwA[2].y + a.z * kwA[2].z + a.w * kwA[2].w
                   + c.x * kwB[2].x + c.y * kwB[2].y + c.z * kwB[2].z + c.w * kwB[2].w;
#pragma unroll
        for (int off = 32; off; off >>= 1) {
            acc0 += __shfl_xor(acc0, off);
            acc1 += __shfl_xor(acc1, off);
            acc2 += __shfl_xor(acc2, off);
        }
        if (lane == 0) {
            dplP[(0 * Bn + b) * DROW + DPAD + t] = acc0;
            dplP[(1 * Bn + b) * DROW + DPAD + t] = acc1;
            dplP[(2 * Bn + b) * DROW + DPAD + t] = acc2;
        }
    }
}

// ---------------- K3a: per-b masked softmax stats (mx, 1/sum)
__global__ __launch_bounds__(256) void k3a_stats(const float* __restrict__ dplP,
                                                 const int* __restrict__ kmask,
                                                 float* __restrict__ stats) {
    const int b = blockIdx.x;
    const int tid = threadIdx.x;
    const float* d0 = dplP + (0 * Bn + b) * DROW + DPAD;
    const float* d1 = dplP + (1 * Bn + b) * DROW + DPAD;
    const float* d2 = dplP + (2 * Bn + b) * DROW + DPAD;

    float av[8];
    int m[8];
    float lmax = -FLT_MAX;
#pragma unroll
    for (int i = 0; i < 8; ++i) {
        int t = tid + i * 256;
        float x0 = d0[t - 1];
        float x2 = d2[t + 1];
        float val = d1[t] + (t > 0 ? x0 : 0.f) + (t < Ln - 1 ? x2 : 0.f);
        av[i] = val;
        m[i] = kmask[t * Bn + b];
        if (m[i]) lmax = fmaxf(lmax, val);
    }
    __shared__ float red[4];
#pragma unroll
    for (int off = 32; off; off >>= 1) lmax = fmaxf(lmax, __shfl_xor(lmax, off));
    if ((tid & 63) == 0) red[tid >> 6] = lmax;
    __syncthreads();
    const float mx = fmaxf(fmaxf(red[0], red[1]), fmaxf(red[2], red[3]));
    __syncthreads();
    float lsum = 0.f;
#pragma unroll
    for (int i = 0; i < 8; ++i) lsum += m[i] ? __expf(av[i] - mx) : 0.f;
#pragma unroll
    for (int off = 32; off; off >>= 1) lsum += __shfl_xor(lsum, off);
    if ((tid & 63) == 0) red[tid >> 6] = lsum;
    __syncthreads();
    if (tid == 0) {
        float s = red[0] + red[1] + red[2] + red[3];
        stats[2 * b] = mx;
        stats[2 * b + 1] = 1.f / s;
    }
}

// ---------------- K3b: emit a/e in [t][b] layout via LDS transpose + eT[b][t]
__global__ __launch_bounds__(256) void k3b_emit(const float* __restrict__ dplP,
                                                const int* __restrict__ kmask,
                                                const float* __restrict__ stats,
                                                float* __restrict__ out_a,
                                                float* __restrict__ out_e,
                                                float* __restrict__ eT) {
    __shared__ float lsa[64][65];
    __shared__ float lse[64][65];
    const int t0 = blockIdx.x * 64;
    const int tid = threadIdx.x;
    const int r = tid >> 4;      // 0..15
    const int c4 = tid & 15;     // f4 column group

    // pass 1: b-major read of tap planes, combine, compute e, write eT, stash tiles
#pragma unroll
    for (int p = 0; p < 4; ++p) {
        const int b = p * 16 + r;
        const float mx = stats[2 * b];
        const float inv = stats[2 * b + 1];
        const float* d0 = dplP + (0 * Bn + b) * DROW + DPAD;
        const float* d1 = dplP + (1 * Bn + b) * DROW + DPAD;
        const float* d2 = dplP + (2 * Bn + b) * DROW + DPAD;
        f4 ev;
#pragma unroll
        for (int i = 0; i < 4; ++i) {
            const int t = t0 + c4 * 4 + i;
            float x0 = d0[t - 1];
            float x2 = d2[t + 1];
            float av = d1[t] + (t > 0 ? x0 : 0.f) + (t < Ln - 1 ? x2 : 0.f);
            const int m = kmask[t * Bn + b];
            ev[i] = m ? __expf(av - mx) * inv : 0.f;
            lsa[b][c4 * 4 + i] = av;
            lse[b][c4 * 4 + i] = ev[i];
        }
        *(f4*)&eT[b * Ln + t0 + c4 * 4] = ev;
    }
    __syncthreads();
    // pass 2: t-major write (full 256B lines)
#pragma unroll
    for (int p = 0; p < 4; ++p) {
        const int t = p * 16 + r;
        f4 oa, oe;
#pragma unroll
        for (int i = 0; i < 4; ++i) {
            oa[i] = lsa[c4 * 4 + i][t];
            oe[i] = lse[c4 * 4 + i][t];
        }
        *(f4*)&out_a[(t0 + t) * Bn + c4 * 4] = oa;
        *(f4*)&out_e[(t0 + t) * Bn + c4 * 4] = oe;
    }
}

// ---------------- K4: sparse PV partials via ballot-skip. block = (t-chunk 256) x b
__global__ __launch_bounds__(256) void k4_pv(const float* __restrict__ v,
                                             const float* __restrict__ eT,
                                             float* __restrict__ vpart) {
    const int c = blockIdx.x >> 6;    // 0..7
    const int b = blockIdx.x & 63;
    const int tid = threadIdx.x;

    __shared__ float es[256];
    __shared__ unsigned long long bm[4];
    const float e = eT[b * Ln + c * 256 + tid];
    es[tid] = e;
    unsigned long long bal = __ballot(e != 0.f);
    if ((tid & 63) == 0) bm[tid >> 6] = bal;
    __syncthreads();

    f2 acc;
    acc.x = 0.f;
    acc.y = 0.f;
#pragma unroll
    for (int w = 0; w < 4; ++w) {
        unsigned long long mm = bm[w];
        while (mm) {
            int bit = __ffsll((unsigned long long)mm) - 1;
            mm &= mm - 1;
            int tt = w * 64 + bit;
            float ee = es[tt];
            const f2* vrow = (const f2*)(v + (((size_t)(c * 256 + tt) * Bn + b) << 9));
            f2 vv = __builtin_nontemporal_load(vrow + tid);
            acc.x += ee * vv.x;
            acc.y += ee * vv.y;
        }
    }
    *(f2*)&vpart[((c * Bn + b) << 9) + tid * 2] = acc;
}

// ---------------- K5: reduce v partials -> attend[b, v]
__global__ __launch_bounds__(256) void k5_reduce(const float* __restrict__ vpart,
                                                 float* __restrict__ out_att) {
    const int idx = blockIdx.x * 256 + threadIdx.x;  // [0, 32768)
    float s = 0.f;
#pragma unroll
    for (int c = 0; c < 8; ++c) s += vpart[c * (Bn * Vn) + idx];
    out_att[idx] = s;
}

extern "C" void kernel_launch(void* const* d_in, const int* in_sizes, int n_in,
                              void* d_out, int out_size, void* d_ws, size_t ws_size,
                              hipStream_t stream) {
    const float* q = (const float*)d_in[0];
    const float* k = (const float*)d_in[1];
    const float* v = (const float*)d_in[2];
    const int* kmask = (const int*)d_in[3];
    const float* W = (const float*)d_in[4];
    const float* bias = (const float*)d_in[5];

    float* out = (float*)d_out;
    float* out_a = out;                      // [L, B]
    float* out_e = out + Ln * Bn;            // [L, B]
    float* out_att = out + 2 * Ln * Bn;      // [B, V]

    float* ws = (float*)d_ws;
    float* kern = ws + OFF_KERN;
    float* dplP = ws + OFF_DPL;
    float* eT = ws + OFF_ET;
    float* stats = ws + OFF_STAT;
    float* scr = ws + OFF_SCR;   // gemm partials, later v partials (disjoint phases)

    k1_gemm<<<dim3(24, 4), 256, 0, stream>>>(q, W, scr);
    k1b_reduce<<<(3 * Bn * Cn + 255) / 256, 256, 0, stream>>>(scr, bias, kern);
    k2_dots<<<4096, 256, 0, stream>>>(k, kern, dplP);
    k3a_stats<<<Bn, 256, 0, stream>>>(dplP, kmask, stats);
    k3b_emit<<<Ln / 64, 256, 0, stream>>>(dplP, kmask, stats, out_a, out_e, eT);
    k4_pv<<<8 * Bn, 256, 0, stream>>>(v, eT, scr);
    k5_reduce<<<(Bn * Vn) / 256, 256, 0, stream>>>(scr, out_att);
}